// Round 22
// baseline (897.259 us; speedup 1.0000x reference)
//
#include <hip/hip_runtime.h>

#define B_ 4
#define C_ 512
#define N_ 4096   // H*W == M (style spatial) == N (content spatial)

typedef unsigned short u16;
typedef _Float16 f16;
typedef f16 f16x8 __attribute__((ext_vector_type(8)));
typedef float f32x4 __attribute__((ext_vector_type(4)));

#define MFMA16(a, b, c) __builtin_amdgcn_mfma_f32_16x16x32_f16(a, b, c, 0, 0, 0)

__device__ __forceinline__ u16 f2h(float f) {
  union { f16 h; u16 u; } x; x.h = (f16)f; return x.u;   // v_cvt_f16_f32, RNE
}
__device__ __forceinline__ float h2f(u16 v) {
  union { u16 u; f16 h; } x; x.u = v; return (float)x.h;
}
__device__ __forceinline__ f16x8 ldA(const void* p) {
  union { uint4 u; f16x8 v; } x; x.u = *(const uint4*)p; return x.v;
}

// ---------------- weights fp32 -> f16 ----------------
__global__ __launch_bounds__(256) void cast_w_kernel(const float* __restrict__ in,
                                                     u16* __restrict__ out, int n) {
  int i = (blockIdx.x * 256 + threadIdx.x) * 4;
  if (i >= n) return;
  float4 v = *(const float4*)(in + i);
  uint2 p;
  p.x = f2h(v.x) | ((unsigned)f2h(v.y) << 16);
  p.y = f2h(v.z) | ((unsigned)f2h(v.w) << 16);
  *(uint2*)(out + i) = p;
}

// ---------------- fp32 [B][C][N] -> f16 [B][N][C] ----------------
__global__ __launch_bounds__(256) void transpose_cast_kernel(const float* __restrict__ in,
                                                             u16* __restrict__ out) {
  __shared__ float ld[64][65];
  const int b = blockIdx.z, n0 = blockIdx.x * 64, c0 = blockIdx.y * 64;
  const int t = threadIdx.x;
  {
    const int r = t >> 2, q4 = (t & 3) * 16;
    const float* ip = in + ((size_t)(b * C_ + c0 + r)) * N_ + n0 + q4;
#pragma unroll
    for (int j = 0; j < 4; ++j) {
      float4 v = *(const float4*)(ip + j * 4);
      ld[r][q4 + j * 4 + 0] = v.x; ld[r][q4 + j * 4 + 1] = v.y;
      ld[r][q4 + j * 4 + 2] = v.z; ld[r][q4 + j * 4 + 3] = v.w;
    }
  }
  __syncthreads();
  {
    const int r2 = t >> 2, c16 = (t & 3) * 16;
    unsigned pk[8];
#pragma unroll
    for (int j = 0; j < 8; ++j) {
      unsigned lo = f2h(ld[c16 + j * 2 + 0][r2]);
      unsigned hi = f2h(ld[c16 + j * 2 + 1][r2]);
      pk[j] = lo | (hi << 16);
    }
    u16* op = out + ((size_t)(b * N_ + n0 + r2)) * C_ + c0 + c16;
    *(uint4*)(op + 0) = make_uint4(pk[0], pk[1], pk[2], pk[3]);
    *(uint4*)(op + 8) = make_uint4(pk[4], pk[5], pk[6], pk[7]);
  }
}

// ---- conv1x1: out[b][n][o] = sum_c Xt[b][n][c]*W[o][c] + bias[o]
//      OutT != null: emit transposed [o][n] instead (for Hv) ----
__global__ __launch_bounds__(512, 4) void conv_kernel(const u16* __restrict__ Xt,
                                                      const u16* __restrict__ Wb,
                                                      const float* __restrict__ bias,
                                                      u16* __restrict__ Outp,
                                                      u16* __restrict__ OutT) {
  __shared__ char sm[65536];
  const int b = blockIdx.z, n0 = blockIdx.x * 64, o0 = blockIdx.y * 64;
  const int t = threadIdx.x, w = t >> 6, lane = t & 63;
  const int wr = w >> 1, wc = w & 1, l15 = lane & 15, l4 = lane >> 4;
#pragma unroll
  for (int k = 0; k < 8; ++k) {
    int ch = t + k * 512, row = ch >> 6, c16 = ch & 63;
    uint4 xv = *(const uint4*)(Xt + ((size_t)(b * N_ + n0 + row)) * C_ + c16 * 8);
    *(uint4*)(sm + row * 1024 + ((c16 ^ (row & 7)) << 4)) = xv;
  }
  __syncthreads();
  f32x4 acc0 = {0, 0, 0, 0}, acc1 = {0, 0, 0, 0};
  const int arow = wr * 16 + l15;
  const int oA = o0 + wc * 32 + l15, oB = oA + 16;
  const u16* wp0 = Wb + (size_t)oA * C_ + l4 * 8;
  const u16* wp1 = Wb + (size_t)oB * C_ + l4 * 8;
#pragma unroll
  for (int kf = 0; kf < 16; ++kf) {
    f16x8 a = ldA(sm + arow * 1024 + (((kf * 4 + l4) ^ (arow & 7)) << 4));
    f16x8 w0 = ldA(wp0 + kf * 32);
    f16x8 w1 = ldA(wp1 + kf * 32);
    acc0 = MFMA16(a, w0, acc0);
    acc1 = MFMA16(a, w1, acc1);
  }
  const float b0 = bias[oA], b1 = bias[oB];
  if (OutT == nullptr) {
#pragma unroll
    for (int r = 0; r < 4; ++r) {
      int n = n0 + wr * 16 + l4 * 4 + r;
      size_t base = ((size_t)(b * N_ + n)) * C_;
      Outp[base + oA] = f2h(acc0[r] + b0);
      Outp[base + oB] = f2h(acc1[r] + b1);
    }
  } else {
    __syncthreads();
    u16* ldsT = (u16*)sm;
#pragma unroll
    for (int r = 0; r < 4; ++r) {
      int nl = wr * 16 + l4 * 4 + r;
      ldsT[(oA - o0) * 72 + nl] = f2h(acc0[r] + b0);
      ldsT[(oB - o0) * 72 + nl] = f2h(acc1[r] + b1);
    }
    __syncthreads();
    const int orow = t >> 3, n8 = (t & 7) * 8;
    uint4 v = *(const uint4*)&ldsT[orow * 72 + n8];
    *(uint4*)(OutT + ((size_t)(b * C_ + o0 + orow)) * N_ + n0 + n8) = v;
  }
}

// ====== fused dual-moment flash attention — producer/consumer waves, KVB=32 ======
// OutM[b][n][c] (f32) = softmax(F G) @ V^T ; OutS = softmax(F G) @ (V^2)^T
// R21 + T5 s_setprio around both MFMA clusters (role diversity per phase exists):
// Phase A: waves 0-3 QK(prio)+in-wave softmax+P; waves 4-11 stage V(it); 12-15 idle.
// B1. Phase B: waves 12-15 tight load+write G(it+1); all waves rescale+dual-PV(prio).
// B2. 2 barriers/iter, zero registers held across barriers, no spill.
#define LQ  0        // Q [64 n][512 c] f16, xor-swizzled 1024B rows   (64K)
#define LG  65536    // G [32 m][512 c] f16, xor-swizzled 1024B rows   (32K)
#define LV  98304    // V [512 c] rows of 80B (32 m f16 + pad)         (40K)
#define LP  139264   // P [64 n] rows of 80B (32 m f16 + pad)          (5K)
#define LF  144384   // fac float[64]
#define LL  144640   // lbuf float[64]

__global__ __launch_bounds__(1024, 4) void attn_dual_kernel(const u16* __restrict__ Ft,
                                                            const u16* __restrict__ Gt,
                                                            const u16* __restrict__ V,
                                                            float* __restrict__ OutM,
                                                            float* __restrict__ OutS) {
  __shared__ char sm[144896];
  char* ldsQ = sm + LQ; char* ldsG = sm + LG; char* ldsV = sm + LV; char* ldsP = sm + LP;
  float* facv = (float*)(sm + LF);
  float* lbuf = (float*)(sm + LL);

  const int b = blockIdx.y, n0 = blockIdx.x * 64;
  const int t = threadIdx.x, w = t >> 6, lane = t & 63;
  const int l15 = lane & 15, l4 = lane >> 4;
  const int ri = w >> 2, ci = w & 3;                    // PV tile: rows ri*16, cols ci*128

  // ---- prologue: stage Q (64K) + G(0) (32K) ----
#pragma unroll
  for (int k = 0; k < 4; ++k) {
    int ch = t + k * 1024, row = ch >> 6, c16 = ch & 63;
    uint4 qv = *(const uint4*)(Ft + ((size_t)(b * N_ + n0 + row)) * C_ + c16 * 8);
    *(uint4*)(ldsQ + row * 1024 + ((c16 ^ (row & 7)) << 4)) = qv;
  }
#pragma unroll
  for (int k = 0; k < 2; ++k) {
    int ch = t + k * 1024, row = ch >> 6, c16 = ch & 63;
    uint4 gv = *(const uint4*)(Gt + ((size_t)(b * N_ + row)) * C_ + c16 * 8);
    *(uint4*)(ldsG + row * 1024 + ((c16 ^ (row & 7)) << 4)) = gv;
  }

  f32x4 accM[8], accS[8];
#pragma unroll
  for (int i = 0; i < 8; ++i) { accM[i] = (f32x4){0,0,0,0}; accS[i] = (f32x4){0,0,0,0}; }
  float m_run[4] = {-1e30f, -1e30f, -1e30f, -1e30f};    // live in waves 0-3 only
  float l_run[4] = {0, 0, 0, 0};

  const u16* Vb = V + (size_t)(b * C_) * N_;
  __syncthreads();                                      // Q + G(0) resident

  for (int it = 0; it < 128; ++it) {
    const int m0 = it * 32;

    // ================= phase A =================
    if (w < 4) {
      // QK: rows w*16..+16, all 32 m; softmax fully in-wave
      f32x4 s0 = {0, 0, 0, 0}, s1 = {0, 0, 0, 0};
      {
        const int qrow = w * 16 + l15;
        const int g0r = l15, g1r = 16 + l15;
        __builtin_amdgcn_s_setprio(1);
#pragma unroll
        for (int kf = 0; kf < 16; ++kf) {
          int c16 = kf * 4 + l4;
          f16x8 qf = ldA(ldsQ + qrow * 1024 + ((c16 ^ (qrow & 7)) << 4));
          f16x8 ga = ldA(ldsG + g0r * 1024 + ((c16 ^ (g0r & 7)) << 4));
          f16x8 gb = ldA(ldsG + g1r * 1024 + ((c16 ^ (g1r & 7)) << 4));
          s0 = MFMA16(qf, ga, s0);
          s1 = MFMA16(qf, gb, s1);
        }
        __builtin_amdgcn_s_setprio(0);
      }
      float rmax[4];
#pragma unroll
      for (int r = 0; r < 4; ++r) rmax[r] = fmaxf(s0[r], s1[r]);
#pragma unroll
      for (int off = 1; off < 16; off <<= 1)
#pragma unroll
        for (int r = 0; r < 4; ++r) rmax[r] = fmaxf(rmax[r], __shfl_xor(rmax[r], off));
      float fac0[4], rsum[4];
#pragma unroll
      for (int r = 0; r < 4; ++r) {
        float mn = fmaxf(m_run[r], rmax[r]);
        fac0[r] = __expf(m_run[r] - mn);
        float p0 = __expf(s0[r] - mn);
        float p1 = __expf(s1[r] - mn);
        u16 pb0 = f2h(p0), pb1 = f2h(p1);
        rsum[r] = h2f(pb0) + h2f(pb1);                  // denominator from ROUNDED p
        int row = w * 16 + l4 * 4 + r;
        *(u16*)(ldsP + row * 80 + l15 * 2) = pb0;
        *(u16*)(ldsP + row * 80 + 32 + l15 * 2) = pb1;
        m_run[r] = mn;
      }
#pragma unroll
      for (int off = 1; off < 16; off <<= 1)
#pragma unroll
        for (int r = 0; r < 4; ++r) rsum[r] += __shfl_xor(rsum[r], off);
      if (l15 == 0)
#pragma unroll
        for (int r = 0; r < 4; ++r) {
          int row = w * 16 + l4 * 4 + r;
          l_run[r] = l_run[r] * fac0[r] + rsum[r];
          facv[row] = fac0[r];
        }
      else
#pragma unroll
        for (int r = 0; r < 4; ++r) l_run[r] = l_run[r] * fac0[r] + rsum[r];
    } else if (w < 12) {
      // stage V(it): 512 threads x 4 chunks of 16B -> [512 c] rows of 80B
      const int t2 = t - 256;
#pragma unroll
      for (int k = 0; k < 4; ++k) {
        int ch = t2 + k * 512, c = ch >> 2, sl = ch & 3;
        uint4 vv = *(const uint4*)(Vb + (size_t)c * N_ + m0 + sl * 8);
        *(uint4*)(ldsV + c * 80 + sl * 16) = vv;
      }
    }
    // waves 12-15: idle in phase A (their staging work happens in phase B)
    __syncthreads();                                    // B1: V + P + fac ready; G reads done

    // ================= phase B =================
    if (w >= 12 && it < 127) {
      // tight load+write G(it+1): latency covered by the other 12 waves' PV
      const int t3 = t - 768;
      const u16* gb_ = Gt + ((size_t)(b * N_ + m0 + 32)) * C_;
#pragma unroll
      for (int k = 0; k < 8; ++k) {
        int ch = t3 + k * 256, row = ch >> 6, c16 = ch & 63;
        uint4 gv = *(const uint4*)(gb_ + (size_t)row * C_ + c16 * 8);
        *(uint4*)(ldsG + row * 1024 + ((c16 ^ (row & 7)) << 4)) = gv;
      }
    }
    // all waves: rescale + dual PV (rows ri*16, cols ci*128)
    float fr[4];
#pragma unroll
    for (int r = 0; r < 4; ++r) fr[r] = facv[ri * 16 + l4 * 4 + r];
    bool nch = true;
#pragma unroll
    for (int r = 0; r < 4; ++r) nch = nch && (fr[r] == 1.0f);
    if (!__all(nch)) {
#pragma unroll
      for (int f = 0; f < 8; ++f)
#pragma unroll
        for (int r = 0; r < 4; ++r) { accM[f][r] *= fr[r]; accS[f][r] *= fr[r]; }
    }
    {
      const int arow = ri * 16 + l15;
      f16x8 a = ldA(ldsP + arow * 80 + l4 * 16);        // k = l4*8 of 32
      __builtin_amdgcn_s_setprio(1);
#pragma unroll
      for (int f = 0; f < 8; ++f) {
        const int c = ci * 128 + f * 16 + l15;
        f16x8 v0 = ldA(ldsV + c * 80 + l4 * 16);
        accM[f] = MFMA16(a, v0, accM[f]);
        f16x8 w0 = v0 * v0;                             // f16 RNE square
        accS[f] = MFMA16(a, w0, accS[f]);
      }
      __builtin_amdgcn_s_setprio(0);
    }
    __syncthreads();                                    // B2: PV reads + G(it+1) writes done
  }

  // ---- epilogue ----
  if (w < 4 && l15 == 0)
#pragma unroll
    for (int r = 0; r < 4; ++r) lbuf[w * 16 + l4 * 4 + r] = l_run[r];
  __syncthreads();
  float rl[4];
#pragma unroll
  for (int r = 0; r < 4; ++r) rl[r] = 1.0f / lbuf[ri * 16 + l4 * 4 + r];
#pragma unroll
  for (int f = 0; f < 8; ++f) {
    const int c = ci * 128 + f * 16 + l15;
#pragma unroll
    for (int r = 0; r < 4; ++r) {
      int n = n0 + ri * 16 + l4 * 4 + r;
      size_t o = ((size_t)(b * N_ + n)) * C_ + c;
      OutM[o] = accM[f][r] * rl[r];
      OutS[o] = accS[f][r] * rl[r];
    }
  }
}

// ---------------- per-(b,c) content stats ----------------
__global__ __launch_bounds__(256) void stats_kernel(const float* __restrict__ content,
                                                    float* __restrict__ stats) {
  const int c = blockIdx.x, b = blockIdx.y;
  const float4* p = (const float4*)(content + ((size_t)(b * C_ + c)) * N_);
  float s = 0.f, ss = 0.f;
  for (int i = threadIdx.x; i < N_ / 4; i += 256) {
    float4 v = p[i];
    s += v.x + v.y + v.z + v.w;
    ss += v.x * v.x + v.y * v.y + v.z * v.z + v.w * v.w;
  }
#pragma unroll
  for (int off = 32; off; off >>= 1) { s += __shfl_down(s, off); ss += __shfl_down(ss, off); }
  __shared__ float as_[4], ass_[4];
  int w = threadIdx.x >> 6;
  if ((threadIdx.x & 63) == 0) { as_[w] = s; ass_[w] = ss; }
  __syncthreads();
  if (threadIdx.x == 0) {
    float S = as_[0] + as_[1] + as_[2] + as_[3];
    float SS = ass_[0] + ass_[1] + ass_[2] + ass_[3];
    float mu = S * (1.0f / N_);
    float var = (SS - (float)N_ * mu * mu) * (1.0f / (N_ - 1));
    stats[(size_t)(b * C_ + c) * 2 + 0] = mu;
    stats[(size_t)(b * C_ + c) * 2 + 1] = rsqrtf(var + 1e-5f);
  }
}

// ---------------- out[b][c][n] = sqrt(relu(sec-mean^2))*(x-mu)*rs + mean ----------------
__global__ __launch_bounds__(256) void combine_kernel(const float* __restrict__ content,
                                                      const float* __restrict__ meanb,
                                                      const float* __restrict__ secb,
                                                      const float* __restrict__ stats,
                                                      float* __restrict__ outp) {
  __shared__ float ldM[64][65], ldS[64][65];
  const int b = blockIdx.z, n0 = blockIdx.x * 64, c0 = blockIdx.y * 64;
  const int t = threadIdx.x;
  {
    const int r = t >> 2, q4 = (t & 3) * 16;
    size_t ib = ((size_t)(b * N_ + n0 + r)) * C_ + c0 + q4;
#pragma unroll
    for (int j = 0; j < 4; ++j) {
      float4 mv = *(const float4*)(meanb + ib + j * 4);
      float4 sv = *(const float4*)(secb + ib + j * 4);
      ldM[r][q4 + j * 4 + 0] = mv.x; ldM[r][q4 + j * 4 + 1] = mv.y;
      ldM[r][q4 + j * 4 + 2] = mv.z; ldM[r][q4 + j * 4 + 3] = mv.w;
      ldS[r][q4 + j * 4 + 0] = sv.x; ldS[r][q4 + j * 4 + 1] = sv.y;
      ldS[r][q4 + j * 4 + 2] = sv.z; ldS[r][q4 + j * 4 + 3] = sv.w;
    }
  }
  __syncthreads();
  const int n4 = (t & 15) * 4, cb = t >> 4;
#pragma unroll
  for (int cc = 0; cc < 4; ++cc) {
    int c_loc = cc * 16 + cb;
    int c = c0 + c_loc;
    float mu = stats[(size_t)(b * C_ + c) * 2 + 0];
    float rs = stats[(size_t)(b * C_ + c) * 2 + 1];
    size_t gb = ((size_t)(b * C_ + c)) * N_ + n0 + n4;
    float4 xv = *(const float4*)(content + gb);
    float4 ov;
    {
      float m0_ = ldM[n4 + 0][c_loc], s0_ = ldS[n4 + 0][c_loc];
      float m1_ = ldM[n4 + 1][c_loc], s1_ = ldS[n4 + 1][c_loc];
      float m2_ = ldM[n4 + 2][c_loc], s2_ = ldS[n4 + 2][c_loc];
      float m3_ = ldM[n4 + 3][c_loc], s3_ = ldS[n4 + 3][c_loc];
      ov.x = sqrtf(fmaxf(s0_ - m0_ * m0_, 0.f)) * ((xv.x - mu) * rs) + m0_;
      ov.y = sqrtf(fmaxf(s1_ - m1_ * m1_, 0.f)) * ((xv.y - mu) * rs) + m1_;
      ov.z = sqrtf(fmaxf(s2_ - m2_ * m2_, 0.f)) * ((xv.z - mu) * rs) + m2_;
      ov.w = sqrtf(fmaxf(s3_ - m3_ * m3_, 0.f)) * ((xv.w - mu) * rs) + m3_;
    }
    *(float4*)(outp + gb) = ov;
  }
}

extern "C" void kernel_launch(void* const* d_in, const int* in_sizes, int n_in,
                              void* d_out, int out_size, void* d_ws, size_t ws_size,
                              hipStream_t stream) {
  (void)in_sizes; (void)n_in; (void)out_size; (void)ws_size;
  const float* content = (const float*)d_in[0];
  const float* style   = (const float*)d_in[1];
  const float* ckey    = (const float*)d_in[2];
  const float* skey    = (const float*)d_in[3];
  const float* Wf = (const float*)d_in[4]; const float* bf_ = (const float*)d_in[5];
  const float* Wg = (const float*)d_in[6]; const float* bg_ = (const float*)d_in[7];
  const float* Wh = (const float*)d_in[8]; const float* bh_ = (const float*)d_in[9];
  float* outp = (float*)d_out;
  char* ws = (char*)d_ws;

  const size_t MB = 1u << 20;
  u16*   Ft    = (u16*)(ws + 0 * MB);    // [B][N][C] f16
  u16*   Gt    = (u16*)(ws + 16 * MB);   // [B][M][C] f16
  u16*   Hv    = (u16*)(ws + 32 * MB);   // [B][C][M] f16 (conv-H transposed epilogue)
  float* stats = (float*)(ws + 48 * MB); // [B][C][2] fp32 (after Xt dead)
  u16*   Xt    = (u16*)(ws + 48 * MB);   // scratch, dead after convH
  float* meanb = (float*)(ws + 64 * MB); // [B][N][C] fp32
  float* secb  = (float*)(ws + 96 * MB); // [B][N][C] fp32
  u16*   Wb3   = (u16*)(ws + 80 * MB);   // weights, dead before attn
  u16* Wbf = Wb3, *Wbg = Wb3 + 262144, *Wbh = Wb3 + 524288;

  const dim3 gT(64, 8, 4);

  cast_w_kernel<<<256, 256, 0, stream>>>(Wf, Wbf, 262144);
  cast_w_kernel<<<256, 256, 0, stream>>>(Wg, Wbg, 262144);
  cast_w_kernel<<<256, 256, 0, stream>>>(Wh, Wbh, 262144);

  transpose_cast_kernel<<<gT, 256, 0, stream>>>(ckey, Xt);
  conv_kernel<<<gT, 512, 0, stream>>>(Xt, Wbf, bf_, Ft, nullptr);
  transpose_cast_kernel<<<gT, 256, 0, stream>>>(skey, Xt);
  conv_kernel<<<gT, 512, 0, stream>>>(Xt, Wbg, bg_, Gt, nullptr);
  transpose_cast_kernel<<<gT, 256, 0, stream>>>(style, Xt);
  conv_kernel<<<gT, 512, 0, stream>>>(Xt, Wbh, bh_, nullptr, Hv);

  stats_kernel<<<dim3(C_, B_), 256, 0, stream>>>(content, stats);
  attn_dual_kernel<<<dim3(64, B_), 1024, 0, stream>>>(Ft, Gt, Hv, meanb, secb);
  combine_kernel<<<gT, 256, 0, stream>>>(content, meanb, secb, stats, outp);
}

// Round 23
// 874.494 us; speedup vs baseline: 1.0260x; 1.0260x over previous
//
#include <hip/hip_runtime.h>

#define B_ 4
#define C_ 512
#define N_ 4096   // H*W == M (style spatial) == N (content spatial)

typedef unsigned short u16;
typedef _Float16 f16;
typedef f16 f16x8 __attribute__((ext_vector_type(8)));
typedef float f32x4 __attribute__((ext_vector_type(4)));

#define MFMA16(a, b, c) __builtin_amdgcn_mfma_f32_16x16x32_f16(a, b, c, 0, 0, 0)

__device__ __forceinline__ u16 f2h(float f) {
  union { f16 h; u16 u; } x; x.h = (f16)f; return x.u;   // v_cvt_f16_f32, RNE
}
__device__ __forceinline__ float h2f(u16 v) {
  union { u16 u; f16 h; } x; x.u = v; return (float)x.h;
}
__device__ __forceinline__ f16x8 ldA(const void* p) {
  union { uint4 u; f16x8 v; } x; x.u = *(const uint4*)p; return x.v;
}

// ---------------- weights fp32 -> f16 ----------------
__global__ __launch_bounds__(256) void cast_w_kernel(const float* __restrict__ in,
                                                     u16* __restrict__ out, int n) {
  int i = (blockIdx.x * 256 + threadIdx.x) * 4;
  if (i >= n) return;
  float4 v = *(const float4*)(in + i);
  uint2 p;
  p.x = f2h(v.x) | ((unsigned)f2h(v.y) << 16);
  p.y = f2h(v.z) | ((unsigned)f2h(v.w) << 16);
  *(uint2*)(out + i) = p;
}

// ====== fused transpose + conv1x1 ======
// X fp32 [B][C][N]; per block: stage A-tile f16 [64 n][512 c] (xor-swizzled) by
// transposing 8 c-chunks through a [64][65] fp32 bounce, then loop 8 o-tiles:
// out[b][n][o] = sum_c A[n][c]*W[o][c] + bias[o]   (OutT != null: emit [o][n]).
// Deletes the separate transpose_cast pass AND the 8x redundant Xt re-staging.
#define FCA 0       // A-tile 64K
#define FCB 65536   // bounce fp32 [64][65] (16640B) / ldsT u16 [64][72] (9216B)

__global__ __launch_bounds__(512, 4) void conv_fused_kernel(const float* __restrict__ X,
                                                            const u16* __restrict__ Wb,
                                                            const float* __restrict__ bias,
                                                            u16* __restrict__ Outp,
                                                            u16* __restrict__ OutT) {
  __shared__ char sm[82176];
  float* ld = (float*)(sm + FCB);                       // [64][65] fp32 bounce
  const int b = blockIdx.y, n0 = blockIdx.x * 64;
  const int t = threadIdx.x, w = t >> 6, lane = t & 63;
  const int wr = w >> 1, wc = w & 1, l15 = lane & 15, l4 = lane >> 4;

  // ---- prologue: transpose-stage A-tile, 8 chunks of 64 c ----
  for (int cc = 0; cc < 8; ++cc) {
    {
      const int r = t >> 3, q8 = (t & 7) * 8;           // r: c-row, q8: n offset
      const float* ip = X + ((size_t)(b * C_ + cc * 64 + r)) * N_ + n0 + q8;
      float4 v0 = *(const float4*)(ip);
      float4 v1 = *(const float4*)(ip + 4);
      float* lr = ld + r * 65 + q8;
      lr[0] = v0.x; lr[1] = v0.y; lr[2] = v0.z; lr[3] = v0.w;
      lr[4] = v1.x; lr[5] = v1.y; lr[6] = v1.z; lr[7] = v1.w;
    }
    __syncthreads();
    {
      const int r2 = t >> 3, c8 = (t & 7) * 8;          // r2: n-row, c8: c offset in chunk
      unsigned pk[4];
#pragma unroll
      for (int j = 0; j < 4; ++j) {
        unsigned lo = f2h(ld[(c8 + j * 2 + 0) * 65 + r2]);
        unsigned hi = f2h(ld[(c8 + j * 2 + 1) * 65 + r2]);
        pk[j] = lo | (hi << 16);
      }
      const int c16 = cc * 8 + (t & 7);
      *(uint4*)(sm + r2 * 1024 + ((c16 ^ (r2 & 7)) << 4)) =
          make_uint4(pk[0], pk[1], pk[2], pk[3]);
    }
    __syncthreads();
  }

  // ---- 8 o-tiles over the resident A-tile ----
  for (int o0 = 0; o0 < 512; o0 += 64) {
    f32x4 acc0 = {0, 0, 0, 0}, acc1 = {0, 0, 0, 0};
    const int arow = wr * 16 + l15;
    const int oA = o0 + wc * 32 + l15, oB = oA + 16;
    const u16* wp0 = Wb + (size_t)oA * C_ + l4 * 8;
    const u16* wp1 = Wb + (size_t)oB * C_ + l4 * 8;
#pragma unroll
    for (int kf = 0; kf < 16; ++kf) {
      f16x8 a = ldA(sm + arow * 1024 + (((kf * 4 + l4) ^ (arow & 7)) << 4));
      f16x8 w0 = ldA(wp0 + kf * 32);
      f16x8 w1 = ldA(wp1 + kf * 32);
      acc0 = MFMA16(a, w0, acc0);
      acc1 = MFMA16(a, w1, acc1);
    }
    const float b0 = bias[oA], b1 = bias[oB];
    if (OutT == nullptr) {
#pragma unroll
      for (int r = 0; r < 4; ++r) {
        int n = n0 + wr * 16 + l4 * 4 + r;
        size_t base = ((size_t)(b * N_ + n)) * C_;
        Outp[base + oA] = f2h(acc0[r] + b0);
        Outp[base + oB] = f2h(acc1[r] + b1);
      }
    } else {
      // transposed epilogue via ldsT (bounce region, dead after prologue)
      u16* ldsT = (u16*)(sm + FCB);
#pragma unroll
      for (int r = 0; r < 4; ++r) {
        int nl = wr * 16 + l4 * 4 + r;
        ldsT[(oA - o0) * 72 + nl] = f2h(acc0[r] + b0);
        ldsT[(oB - o0) * 72 + nl] = f2h(acc1[r] + b1);
      }
      __syncthreads();
      const int orow = t >> 3, n8 = (t & 7) * 8;
      uint4 v = *(const uint4*)&ldsT[orow * 72 + n8];
      *(uint4*)(OutT + ((size_t)(b * C_ + o0 + orow)) * N_ + n0 + n8) = v;
      __syncthreads();                                  // before next o-iter reuses ldsT
    }
  }
}

// ====== fused dual-moment flash attention — producer/consumer waves, KVB=32 ======
// OutM[b][n][c] (f32) = softmax(F G) @ V^T ; OutS = softmax(F G) @ (V^2)^T
// R21 (session-best, all canaries clean): zero registers held across barriers.
// Phase A: waves 0-3 QK+in-wave softmax+P; waves 4-11 stage V(it); 12-15 idle.
// B1. Phase B: waves 12-15 tight load+write G(it+1) (covered by 12 PV waves);
// all waves rescale + dual-PV. B2. 2 barriers/iter, no spill.
#define LQ  0        // Q [64 n][512 c] f16, xor-swizzled 1024B rows   (64K)
#define LG  65536    // G [32 m][512 c] f16, xor-swizzled 1024B rows   (32K)
#define LV  98304    // V [512 c] rows of 80B (32 m f16 + pad)         (40K)
#define LP  139264   // P [64 n] rows of 80B (32 m f16 + pad)          (5K)
#define LF  144384   // fac float[64]
#define LL  144640   // lbuf float[64]

__global__ __launch_bounds__(1024, 4) void attn_dual_kernel(const u16* __restrict__ Ft,
                                                            const u16* __restrict__ Gt,
                                                            const u16* __restrict__ V,
                                                            float* __restrict__ OutM,
                                                            float* __restrict__ OutS) {
  __shared__ char sm[144896];
  char* ldsQ = sm + LQ; char* ldsG = sm + LG; char* ldsV = sm + LV; char* ldsP = sm + LP;
  float* facv = (float*)(sm + LF);
  float* lbuf = (float*)(sm + LL);

  const int b = blockIdx.y, n0 = blockIdx.x * 64;
  const int t = threadIdx.x, w = t >> 6, lane = t & 63;
  const int l15 = lane & 15, l4 = lane >> 4;
  const int ri = w >> 2, ci = w & 3;                    // PV tile: rows ri*16, cols ci*128

  // ---- prologue: stage Q (64K) + G(0) (32K) ----
#pragma unroll
  for (int k = 0; k < 4; ++k) {
    int ch = t + k * 1024, row = ch >> 6, c16 = ch & 63;
    uint4 qv = *(const uint4*)(Ft + ((size_t)(b * N_ + n0 + row)) * C_ + c16 * 8);
    *(uint4*)(ldsQ + row * 1024 + ((c16 ^ (row & 7)) << 4)) = qv;
  }
#pragma unroll
  for (int k = 0; k < 2; ++k) {
    int ch = t + k * 1024, row = ch >> 6, c16 = ch & 63;
    uint4 gv = *(const uint4*)(Gt + ((size_t)(b * N_ + row)) * C_ + c16 * 8);
    *(uint4*)(ldsG + row * 1024 + ((c16 ^ (row & 7)) << 4)) = gv;
  }

  f32x4 accM[8], accS[8];
#pragma unroll
  for (int i = 0; i < 8; ++i) { accM[i] = (f32x4){0,0,0,0}; accS[i] = (f32x4){0,0,0,0}; }
  float m_run[4] = {-1e30f, -1e30f, -1e30f, -1e30f};    // live in waves 0-3 only
  float l_run[4] = {0, 0, 0, 0};

  const u16* Vb = V + (size_t)(b * C_) * N_;
  __syncthreads();                                      // Q + G(0) resident

  for (int it = 0; it < 128; ++it) {
    const int m0 = it * 32;

    // ================= phase A =================
    if (w < 4) {
      // QK: rows w*16..+16, all 32 m; softmax fully in-wave
      f32x4 s0 = {0, 0, 0, 0}, s1 = {0, 0, 0, 0};
      {
        const int qrow = w * 16 + l15;
        const int g0r = l15, g1r = 16 + l15;
#pragma unroll
        for (int kf = 0; kf < 16; ++kf) {
          int c16 = kf * 4 + l4;
          f16x8 qf = ldA(ldsQ + qrow * 1024 + ((c16 ^ (qrow & 7)) << 4));
          f16x8 ga = ldA(ldsG + g0r * 1024 + ((c16 ^ (g0r & 7)) << 4));
          f16x8 gb = ldA(ldsG + g1r * 1024 + ((c16 ^ (g1r & 7)) << 4));
          s0 = MFMA16(qf, ga, s0);
          s1 = MFMA16(qf, gb, s1);
        }
      }
      float rmax[4];
#pragma unroll
      for (int r = 0; r < 4; ++r) rmax[r] = fmaxf(s0[r], s1[r]);
#pragma unroll
      for (int off = 1; off < 16; off <<= 1)
#pragma unroll
        for (int r = 0; r < 4; ++r) rmax[r] = fmaxf(rmax[r], __shfl_xor(rmax[r], off));
      float fac0[4], rsum[4];
#pragma unroll
      for (int r = 0; r < 4; ++r) {
        float mn = fmaxf(m_run[r], rmax[r]);
        fac0[r] = __expf(m_run[r] - mn);
        float p0 = __expf(s0[r] - mn);
        float p1 = __expf(s1[r] - mn);
        u16 pb0 = f2h(p0), pb1 = f2h(p1);
        rsum[r] = h2f(pb0) + h2f(pb1);                  // denominator from ROUNDED p
        int row = w * 16 + l4 * 4 + r;
        *(u16*)(ldsP + row * 80 + l15 * 2) = pb0;
        *(u16*)(ldsP + row * 80 + 32 + l15 * 2) = pb1;
        m_run[r] = mn;
      }
#pragma unroll
      for (int off = 1; off < 16; off <<= 1)
#pragma unroll
        for (int r = 0; r < 4; ++r) rsum[r] += __shfl_xor(rsum[r], off);
      if (l15 == 0)
#pragma unroll
        for (int r = 0; r < 4; ++r) {
          int row = w * 16 + l4 * 4 + r;
          l_run[r] = l_run[r] * fac0[r] + rsum[r];
          facv[row] = fac0[r];
        }
      else
#pragma unroll
        for (int r = 0; r < 4; ++r) l_run[r] = l_run[r] * fac0[r] + rsum[r];
    } else if (w < 12) {
      // stage V(it): 512 threads x 4 chunks of 16B -> [512 c] rows of 80B
      const int t2 = t - 256;
#pragma unroll
      for (int k = 0; k < 4; ++k) {
        int ch = t2 + k * 512, c = ch >> 2, sl = ch & 3;
        uint4 vv = *(const uint4*)(Vb + (size_t)c * N_ + m0 + sl * 8);
        *(uint4*)(ldsV + c * 80 + sl * 16) = vv;
      }
    }
    // waves 12-15: idle in phase A (their staging work happens in phase B)
    __syncthreads();                                    // B1: V + P + fac ready; G reads done

    // ================= phase B =================
    if (w >= 12 && it < 127) {
      // tight load+write G(it+1): latency covered by the other 12 waves' PV
      const int t3 = t - 768;
      const u16* gb_ = Gt + ((size_t)(b * N_ + m0 + 32)) * C_;
#pragma unroll
      for (int k = 0; k < 8; ++k) {
        int ch = t3 + k * 256, row = ch >> 6, c16 = ch & 63;
        uint4 gv = *(const uint4*)(gb_ + (size_t)row * C_ + c16 * 8);
        *(uint4*)(ldsG + row * 1024 + ((c16 ^ (row & 7)) << 4)) = gv;
      }
    }
    // all waves: rescale + dual PV (rows ri*16, cols ci*128)
    float fr[4];
#pragma unroll
    for (int r = 0; r < 4; ++r) fr[r] = facv[ri * 16 + l4 * 4 + r];
    bool nch = true;
#pragma unroll
    for (int r = 0; r < 4; ++r) nch = nch && (fr[r] == 1.0f);
    if (!__all(nch)) {
#pragma unroll
      for (int f = 0; f < 8; ++f)
#pragma unroll
        for (int r = 0; r < 4; ++r) { accM[f][r] *= fr[r]; accS[f][r] *= fr[r]; }
    }
    {
      const int arow = ri * 16 + l15;
      f16x8 a = ldA(ldsP + arow * 80 + l4 * 16);        // k = l4*8 of 32
#pragma unroll
      for (int f = 0; f < 8; ++f) {
        const int c = ci * 128 + f * 16 + l15;
        f16x8 v0 = ldA(ldsV + c * 80 + l4 * 16);
        accM[f] = MFMA16(a, v0, accM[f]);
        f16x8 w0 = v0 * v0;                             // f16 RNE square
        accS[f] = MFMA16(a, w0, accS[f]);
      }
    }
    __syncthreads();                                    // B2: PV reads + G(it+1) writes done
  }

  // ---- epilogue ----
  if (w < 4 && l15 == 0)
#pragma unroll
    for (int r = 0; r < 4; ++r) lbuf[w * 16 + l4 * 4 + r] = l_run[r];
  __syncthreads();
  float rl[4];
#pragma unroll
  for (int r = 0; r < 4; ++r) rl[r] = 1.0f / lbuf[ri * 16 + l4 * 4 + r];
#pragma unroll
  for (int f = 0; f < 8; ++f) {
    const int c = ci * 128 + f * 16 + l15;
#pragma unroll
    for (int r = 0; r < 4; ++r) {
      int n = n0 + ri * 16 + l4 * 4 + r;
      size_t o = ((size_t)(b * N_ + n)) * C_ + c;
      OutM[o] = accM[f][r] * rl[r];
      OutS[o] = accS[f][r] * rl[r];
    }
  }
}

// ---------------- per-(b,c) content stats ----------------
__global__ __launch_bounds__(256) void stats_kernel(const float* __restrict__ content,
                                                    float* __restrict__ stats) {
  const int c = blockIdx.x, b = blockIdx.y;
  const float4* p = (const float4*)(content + ((size_t)(b * C_ + c)) * N_);
  float s = 0.f, ss = 0.f;
  for (int i = threadIdx.x; i < N_ / 4; i += 256) {
    float4 v = p[i];
    s += v.x + v.y + v.z + v.w;
    ss += v.x * v.x + v.y * v.y + v.z * v.z + v.w * v.w;
  }
#pragma unroll
  for (int off = 32; off; off >>= 1) { s += __shfl_down(s, off); ss += __shfl_down(ss, off); }
  __shared__ float as_[4], ass_[4];
  int w = threadIdx.x >> 6;
  if ((threadIdx.x & 63) == 0) { as_[w] = s; ass_[w] = ss; }
  __syncthreads();
  if (threadIdx.x == 0) {
    float S = as_[0] + as_[1] + as_[2] + as_[3];
    float SS = ass_[0] + ass_[1] + ass_[2] + ass_[3];
    float mu = S * (1.0f / N_);
    float var = (SS - (float)N_ * mu * mu) * (1.0f / (N_ - 1));
    stats[(size_t)(b * C_ + c) * 2 + 0] = mu;
    stats[(size_t)(b * C_ + c) * 2 + 1] = rsqrtf(var + 1e-5f);
  }
}

// ---------------- out[b][c][n] = sqrt(relu(sec-mean^2))*(x-mu)*rs + mean ----------------
__global__ __launch_bounds__(256) void combine_kernel(const float* __restrict__ content,
                                                      const float* __restrict__ meanb,
                                                      const float* __restrict__ secb,
                                                      const float* __restrict__ stats,
                                                      float* __restrict__ outp) {
  __shared__ float ldM[64][65], ldS[64][65];
  const int b = blockIdx.z, n0 = blockIdx.x * 64, c0 = blockIdx.y * 64;
  const int t = threadIdx.x;
  {
    const int r = t >> 2, q4 = (t & 3) * 16;
    size_t ib = ((size_t)(b * N_ + n0 + r)) * C_ + c0 + q4;
#pragma unroll
    for (int j = 0; j < 4; ++j) {
      float4 mv = *(const float4*)(meanb + ib + j * 4);
      float4 sv = *(const float4*)(secb + ib + j * 4);
      ldM[r][q4 + j * 4 + 0] = mv.x; ldM[r][q4 + j * 4 + 1] = mv.y;
      ldM[r][q4 + j * 4 + 2] = mv.z; ldM[r][q4 + j * 4 + 3] = mv.w;
      ldS[r][q4 + j * 4 + 0] = sv.x; ldS[r][q4 + j * 4 + 1] = sv.y;
      ldS[r][q4 + j * 4 + 2] = sv.z; ldS[r][q4 + j * 4 + 3] = sv.w;
    }
  }
  __syncthreads();
  const int n4 = (t & 15) * 4, cb = t >> 4;
#pragma unroll
  for (int cc = 0; cc < 4; ++cc) {
    int c_loc = cc * 16 + cb;
    int c = c0 + c_loc;
    float mu = stats[(size_t)(b * C_ + c) * 2 + 0];
    float rs = stats[(size_t)(b * C_ + c) * 2 + 1];
    size_t gb = ((size_t)(b * C_ + c)) * N_ + n0 + n4;
    float4 xv = *(const float4*)(content + gb);
    float4 ov;
    {
      float m0_ = ldM[n4 + 0][c_loc], s0_ = ldS[n4 + 0][c_loc];
      float m1_ = ldM[n4 + 1][c_loc], s1_ = ldS[n4 + 1][c_loc];
      float m2_ = ldM[n4 + 2][c_loc], s2_ = ldS[n4 + 2][c_loc];
      float m3_ = ldM[n4 + 3][c_loc], s3_ = ldS[n4 + 3][c_loc];
      ov.x = sqrtf(fmaxf(s0_ - m0_ * m0_, 0.f)) * ((xv.x - mu) * rs) + m0_;
      ov.y = sqrtf(fmaxf(s1_ - m1_ * m1_, 0.f)) * ((xv.y - mu) * rs) + m1_;
      ov.z = sqrtf(fmaxf(s2_ - m2_ * m2_, 0.f)) * ((xv.z - mu) * rs) + m2_;
      ov.w = sqrtf(fmaxf(s3_ - m3_ * m3_, 0.f)) * ((xv.w - mu) * rs) + m3_;
    }
    *(float4*)(outp + gb) = ov;
  }
}

extern "C" void kernel_launch(void* const* d_in, const int* in_sizes, int n_in,
                              void* d_out, int out_size, void* d_ws, size_t ws_size,
                              hipStream_t stream) {
  (void)in_sizes; (void)n_in; (void)out_size; (void)ws_size;
  const float* content = (const float*)d_in[0];
  const float* style   = (const float*)d_in[1];
  const float* ckey    = (const float*)d_in[2];
  const float* skey    = (const float*)d_in[3];
  const float* Wf = (const float*)d_in[4]; const float* bf_ = (const float*)d_in[5];
  const float* Wg = (const float*)d_in[6]; const float* bg_ = (const float*)d_in[7];
  const float* Wh = (const float*)d_in[8]; const float* bh_ = (const float*)d_in[9];
  float* outp = (float*)d_out;
  char* ws = (char*)d_ws;

  const size_t MB = 1u << 20;
  u16*   Ft    = (u16*)(ws + 0 * MB);    // [B][N][C] f16
  u16*   Gt    = (u16*)(ws + 16 * MB);   // [B][M][C] f16
  u16*   Hv    = (u16*)(ws + 32 * MB);   // [B][C][M] f16 (conv-H transposed epilogue)
  float* stats = (float*)(ws + 48 * MB); // [B][C][2] fp32
  float* meanb = (float*)(ws + 64 * MB); // [B][N][C] fp32
  float* secb  = (float*)(ws + 96 * MB); // [B][N][C] fp32
  u16*   Wb3   = (u16*)(ws + 80 * MB);   // weights f16, dead before attn
  u16* Wbf = Wb3, *Wbg = Wb3 + 262144, *Wbh = Wb3 + 524288;

  const dim3 gT(64, 8, 4);
  const dim3 gC(64, B_);

  cast_w_kernel<<<256, 256, 0, stream>>>(Wf, Wbf, 262144);
  cast_w_kernel<<<256, 256, 0, stream>>>(Wg, Wbg, 262144);
  cast_w_kernel<<<256, 256, 0, stream>>>(Wh, Wbh, 262144);

  conv_fused_kernel<<<gC, 512, 0, stream>>>(ckey, Wbf, bf_, Ft, nullptr);
  conv_fused_kernel<<<gC, 512, 0, stream>>>(skey, Wbg, bg_, Gt, nullptr);
  conv_fused_kernel<<<gC, 512, 0, stream>>>(style, Wbh, bh_, nullptr, Hv);

  stats_kernel<<<dim3(C_, B_), 256, 0, stream>>>(content, stats);
  attn_dual_kernel<<<dim3(64, B_), 1024, 0, stream>>>(Ft, Gt, Hv, meanb, secb);
  combine_kernel<<<gT, 256, 0, stream>>>(content, meanb, secb, stats, outp);
}

// Round 24
// 863.655 us; speedup vs baseline: 1.0389x; 1.0126x over previous
//
#include <hip/hip_runtime.h>

#define B_ 4
#define C_ 512
#define N_ 4096   // H*W == M (style spatial) == N (content spatial)

typedef unsigned short u16;
typedef _Float16 f16;
typedef f16 f16x8 __attribute__((ext_vector_type(8)));
typedef float f32x4 __attribute__((ext_vector_type(4)));

#define MFMA16(a, b, c) __builtin_amdgcn_mfma_f32_16x16x32_f16(a, b, c, 0, 0, 0)

__device__ __forceinline__ u16 f2h(float f) {
  union { f16 h; u16 u; } x; x.h = (f16)f; return x.u;   // v_cvt_f16_f32, RNE
}
__device__ __forceinline__ float h2f(u16 v) {
  union { u16 u; f16 h; } x; x.u = v; return (float)x.h;
}
__device__ __forceinline__ f16x8 ldA(const void* p) {
  union { uint4 u; f16x8 v; } x; x.u = *(const uint4*)p; return x.v;
}

// ---------------- weights fp32 -> f16 ----------------
__global__ __launch_bounds__(256) void cast_w_kernel(const float* __restrict__ in,
                                                     u16* __restrict__ out, int n) {
  int i = (blockIdx.x * 256 + threadIdx.x) * 4;
  if (i >= n) return;
  float4 v = *(const float4*)(in + i);
  uint2 p;
  p.x = f2h(v.x) | ((unsigned)f2h(v.y) << 16);
  p.y = f2h(v.z) | ((unsigned)f2h(v.w) << 16);
  *(uint2*)(out + i) = p;
}

// ====== fused transpose + conv1x1 ======
// X fp32 [B][C][N]; per block: stage A-tile f16 [64 n][512 c] (xor-swizzled) by
// transposing 8 c-chunks through a [64][65] fp32 bounce, then loop 8 o-tiles:
// out[b][n][o] = sum_c A[n][c]*W[o][c] + bias[o]   (OutT != null: emit [o][n]).
#define FCA 0       // A-tile 64K
#define FCB 65536   // bounce fp32 [64][65] (16640B) / ldsT u16 [64][72] (9216B)

__global__ __launch_bounds__(512, 4) void conv_fused_kernel(const float* __restrict__ X,
                                                            const u16* __restrict__ Wb,
                                                            const float* __restrict__ bias,
                                                            u16* __restrict__ Outp,
                                                            u16* __restrict__ OutT) {
  __shared__ char sm[82176];
  float* ld = (float*)(sm + FCB);                       // [64][65] fp32 bounce
  const int b = blockIdx.y, n0 = blockIdx.x * 64;
  const int t = threadIdx.x, w = t >> 6, lane = t & 63;
  const int wr = w >> 1, wc = w & 1, l15 = lane & 15, l4 = lane >> 4;

  // ---- prologue: transpose-stage A-tile, 8 chunks of 64 c ----
  for (int cc = 0; cc < 8; ++cc) {
    {
      const int r = t >> 3, q8 = (t & 7) * 8;           // r: c-row, q8: n offset
      const float* ip = X + ((size_t)(b * C_ + cc * 64 + r)) * N_ + n0 + q8;
      float4 v0 = *(const float4*)(ip);
      float4 v1 = *(const float4*)(ip + 4);
      float* lr = ld + r * 65 + q8;
      lr[0] = v0.x; lr[1] = v0.y; lr[2] = v0.z; lr[3] = v0.w;
      lr[4] = v1.x; lr[5] = v1.y; lr[6] = v1.z; lr[7] = v1.w;
    }
    __syncthreads();
    {
      const int r2 = t >> 3, c8 = (t & 7) * 8;          // r2: n-row, c8: c offset in chunk
      unsigned pk[4];
#pragma unroll
      for (int j = 0; j < 4; ++j) {
        unsigned lo = f2h(ld[(c8 + j * 2 + 0) * 65 + r2]);
        unsigned hi = f2h(ld[(c8 + j * 2 + 1) * 65 + r2]);
        pk[j] = lo | (hi << 16);
      }
      const int c16 = cc * 8 + (t & 7);
      *(uint4*)(sm + r2 * 1024 + ((c16 ^ (r2 & 7)) << 4)) =
          make_uint4(pk[0], pk[1], pk[2], pk[3]);
    }
    __syncthreads();
  }

  // ---- 8 o-tiles over the resident A-tile ----
  for (int o0 = 0; o0 < 512; o0 += 64) {
    f32x4 acc0 = {0, 0, 0, 0}, acc1 = {0, 0, 0, 0};
    const int arow = wr * 16 + l15;
    const int oA = o0 + wc * 32 + l15, oB = oA + 16;
    const u16* wp0 = Wb + (size_t)oA * C_ + l4 * 8;
    const u16* wp1 = Wb + (size_t)oB * C_ + l4 * 8;
#pragma unroll
    for (int kf = 0; kf < 16; ++kf) {
      f16x8 a = ldA(sm + arow * 1024 + (((kf * 4 + l4) ^ (arow & 7)) << 4));
      f16x8 w0 = ldA(wp0 + kf * 32);
      f16x8 w1 = ldA(wp1 + kf * 32);
      acc0 = MFMA16(a, w0, acc0);
      acc1 = MFMA16(a, w1, acc1);
    }
    const float b0 = bias[oA], b1 = bias[oB];
    if (OutT == nullptr) {
#pragma unroll
      for (int r = 0; r < 4; ++r) {
        int n = n0 + wr * 16 + l4 * 4 + r;
        size_t base = ((size_t)(b * N_ + n)) * C_;
        Outp[base + oA] = f2h(acc0[r] + b0);
        Outp[base + oB] = f2h(acc1[r] + b1);
      }
    } else {
      // transposed epilogue via ldsT (bounce region, dead after prologue)
      u16* ldsT = (u16*)(sm + FCB);
#pragma unroll
      for (int r = 0; r < 4; ++r) {
        int nl = wr * 16 + l4 * 4 + r;
        ldsT[(oA - o0) * 72 + nl] = f2h(acc0[r] + b0);
        ldsT[(oB - o0) * 72 + nl] = f2h(acc1[r] + b1);
      }
      __syncthreads();
      const int orow = t >> 3, n8 = (t & 7) * 8;
      uint4 v = *(const uint4*)&ldsT[orow * 72 + n8];
      *(uint4*)(OutT + ((size_t)(b * C_ + o0 + orow)) * N_ + n0 + n8) = v;
      __syncthreads();                                  // before next o-iter reuses ldsT
    }
  }
}

// ====== fused dual-moment flash attention — producer/consumer waves, KVB=32 ======
// OutM[b][n][c] (f16) = softmax(F G) @ V^T ; OutS = softmax(F G) @ (V^2)^T
// R21 structure: Phase A: waves 0-3 QK+in-wave softmax+P; waves 4-11 stage V(it);
// 12-15 idle. B1. Phase B: waves 12-15 tight load+write G(it+1) (covered by 12 PV
// waves); all waves rescale + dual-PV. B2. 2 barriers/iter, no spill.
// f16 outputs (R11-precedent: absmax <= 0.0625, threshold 0.085).
#define LQ  0        // Q [64 n][512 c] f16, xor-swizzled 1024B rows   (64K)
#define LG  65536    // G [32 m][512 c] f16, xor-swizzled 1024B rows   (32K)
#define LV  98304    // V [512 c] rows of 80B (32 m f16 + pad)         (40K)
#define LP  139264   // P [64 n] rows of 80B (32 m f16 + pad)          (5K)
#define LF  144384   // fac float[64]
#define LL  144640   // lbuf float[64]

__global__ __launch_bounds__(1024, 4) void attn_dual_kernel(const u16* __restrict__ Ft,
                                                            const u16* __restrict__ Gt,
                                                            const u16* __restrict__ V,
                                                            u16* __restrict__ OutM,
                                                            u16* __restrict__ OutS) {
  __shared__ char sm[144896];
  char* ldsQ = sm + LQ; char* ldsG = sm + LG; char* ldsV = sm + LV; char* ldsP = sm + LP;
  float* facv = (float*)(sm + LF);
  float* lbuf = (float*)(sm + LL);

  const int b = blockIdx.y, n0 = blockIdx.x * 64;
  const int t = threadIdx.x, w = t >> 6, lane = t & 63;
  const int l15 = lane & 15, l4 = lane >> 4;
  const int ri = w >> 2, ci = w & 3;                    // PV tile: rows ri*16, cols ci*128

  // ---- prologue: stage Q (64K) + G(0) (32K) ----
#pragma unroll
  for (int k = 0; k < 4; ++k) {
    int ch = t + k * 1024, row = ch >> 6, c16 = ch & 63;
    uint4 qv = *(const uint4*)(Ft + ((size_t)(b * N_ + n0 + row)) * C_ + c16 * 8);
    *(uint4*)(ldsQ + row * 1024 + ((c16 ^ (row & 7)) << 4)) = qv;
  }
#pragma unroll
  for (int k = 0; k < 2; ++k) {
    int ch = t + k * 1024, row = ch >> 6, c16 = ch & 63;
    uint4 gv = *(const uint4*)(Gt + ((size_t)(b * N_ + row)) * C_ + c16 * 8);
    *(uint4*)(ldsG + row * 1024 + ((c16 ^ (row & 7)) << 4)) = gv;
  }

  f32x4 accM[8], accS[8];
#pragma unroll
  for (int i = 0; i < 8; ++i) { accM[i] = (f32x4){0,0,0,0}; accS[i] = (f32x4){0,0,0,0}; }
  float m_run[4] = {-1e30f, -1e30f, -1e30f, -1e30f};    // live in waves 0-3 only
  float l_run[4] = {0, 0, 0, 0};

  const u16* Vb = V + (size_t)(b * C_) * N_;
  __syncthreads();                                      // Q + G(0) resident

  for (int it = 0; it < 128; ++it) {
    const int m0 = it * 32;

    // ================= phase A =================
    if (w < 4) {
      // QK: rows w*16..+16, all 32 m; softmax fully in-wave
      f32x4 s0 = {0, 0, 0, 0}, s1 = {0, 0, 0, 0};
      {
        const int qrow = w * 16 + l15;
        const int g0r = l15, g1r = 16 + l15;
#pragma unroll
        for (int kf = 0; kf < 16; ++kf) {
          int c16 = kf * 4 + l4;
          f16x8 qf = ldA(ldsQ + qrow * 1024 + ((c16 ^ (qrow & 7)) << 4));
          f16x8 ga = ldA(ldsG + g0r * 1024 + ((c16 ^ (g0r & 7)) << 4));
          f16x8 gb = ldA(ldsG + g1r * 1024 + ((c16 ^ (g1r & 7)) << 4));
          s0 = MFMA16(qf, ga, s0);
          s1 = MFMA16(qf, gb, s1);
        }
      }
      float rmax[4];
#pragma unroll
      for (int r = 0; r < 4; ++r) rmax[r] = fmaxf(s0[r], s1[r]);
#pragma unroll
      for (int off = 1; off < 16; off <<= 1)
#pragma unroll
        for (int r = 0; r < 4; ++r) rmax[r] = fmaxf(rmax[r], __shfl_xor(rmax[r], off));
      float fac0[4], rsum[4];
#pragma unroll
      for (int r = 0; r < 4; ++r) {
        float mn = fmaxf(m_run[r], rmax[r]);
        fac0[r] = __expf(m_run[r] - mn);
        float p0 = __expf(s0[r] - mn);
        float p1 = __expf(s1[r] - mn);
        u16 pb0 = f2h(p0), pb1 = f2h(p1);
        rsum[r] = h2f(pb0) + h2f(pb1);                  // denominator from ROUNDED p
        int row = w * 16 + l4 * 4 + r;
        *(u16*)(ldsP + row * 80 + l15 * 2) = pb0;
        *(u16*)(ldsP + row * 80 + 32 + l15 * 2) = pb1;
        m_run[r] = mn;
      }
#pragma unroll
      for (int off = 1; off < 16; off <<= 1)
#pragma unroll
        for (int r = 0; r < 4; ++r) rsum[r] += __shfl_xor(rsum[r], off);
      if (l15 == 0)
#pragma unroll
        for (int r = 0; r < 4; ++r) {
          int row = w * 16 + l4 * 4 + r;
          l_run[r] = l_run[r] * fac0[r] + rsum[r];
          facv[row] = fac0[r];
        }
      else
#pragma unroll
        for (int r = 0; r < 4; ++r) l_run[r] = l_run[r] * fac0[r] + rsum[r];
    } else if (w < 12) {
      // stage V(it): 512 threads x 4 chunks of 16B -> [512 c] rows of 80B
      const int t2 = t - 256;
#pragma unroll
      for (int k = 0; k < 4; ++k) {
        int ch = t2 + k * 512, c = ch >> 2, sl = ch & 3;
        uint4 vv = *(const uint4*)(Vb + (size_t)c * N_ + m0 + sl * 8);
        *(uint4*)(ldsV + c * 80 + sl * 16) = vv;
      }
    }
    // waves 12-15: idle in phase A (their staging work happens in phase B)
    __syncthreads();                                    // B1: V + P + fac ready; G reads done

    // ================= phase B =================
    if (w >= 12 && it < 127) {
      // tight load+write G(it+1): latency covered by the other 12 waves' PV
      const int t3 = t - 768;
      const u16* gb_ = Gt + ((size_t)(b * N_ + m0 + 32)) * C_;
#pragma unroll
      for (int k = 0; k < 8; ++k) {
        int ch = t3 + k * 256, row = ch >> 6, c16 = ch & 63;
        uint4 gv = *(const uint4*)(gb_ + (size_t)row * C_ + c16 * 8);
        *(uint4*)(ldsG + row * 1024 + ((c16 ^ (row & 7)) << 4)) = gv;
      }
    }
    // all waves: rescale + dual PV (rows ri*16, cols ci*128)
    float fr[4];
#pragma unroll
    for (int r = 0; r < 4; ++r) fr[r] = facv[ri * 16 + l4 * 4 + r];
    bool nch = true;
#pragma unroll
    for (int r = 0; r < 4; ++r) nch = nch && (fr[r] == 1.0f);
    if (!__all(nch)) {
#pragma unroll
      for (int f = 0; f < 8; ++f)
#pragma unroll
        for (int r = 0; r < 4; ++r) { accM[f][r] *= fr[r]; accS[f][r] *= fr[r]; }
    }
    {
      const int arow = ri * 16 + l15;
      f16x8 a = ldA(ldsP + arow * 80 + l4 * 16);        // k = l4*8 of 32
#pragma unroll
      for (int f = 0; f < 8; ++f) {
        const int c = ci * 128 + f * 16 + l15;
        f16x8 v0 = ldA(ldsV + c * 80 + l4 * 16);
        accM[f] = MFMA16(a, v0, accM[f]);
        f16x8 w0 = v0 * v0;                             // f16 RNE square
        accS[f] = MFMA16(a, w0, accS[f]);
      }
    }
    __syncthreads();                                    // B2: PV reads + G(it+1) writes done
  }

  // ---- epilogue: f16 outputs ----
  if (w < 4 && l15 == 0)
#pragma unroll
    for (int r = 0; r < 4; ++r) lbuf[w * 16 + l4 * 4 + r] = l_run[r];
  __syncthreads();
  float rl[4];
#pragma unroll
  for (int r = 0; r < 4; ++r) rl[r] = 1.0f / lbuf[ri * 16 + l4 * 4 + r];
#pragma unroll
  for (int f = 0; f < 8; ++f) {
    const int c = ci * 128 + f * 16 + l15;
#pragma unroll
    for (int r = 0; r < 4; ++r) {
      int n = n0 + ri * 16 + l4 * 4 + r;
      size_t o = ((size_t)(b * N_ + n)) * C_ + c;
      OutM[o] = f2h(accM[f][r] * rl[r]);
      OutS[o] = f2h(accS[f][r] * rl[r]);
    }
  }
}

// ---------------- per-(b,c) content stats ----------------
__global__ __launch_bounds__(256) void stats_kernel(const float* __restrict__ content,
                                                    float* __restrict__ stats) {
  const int c = blockIdx.x, b = blockIdx.y;
  const float4* p = (const float4*)(content + ((size_t)(b * C_ + c)) * N_);
  float s = 0.f, ss = 0.f;
  for (int i = threadIdx.x; i < N_ / 4; i += 256) {
    float4 v = p[i];
    s += v.x + v.y + v.z + v.w;
    ss += v.x * v.x + v.y * v.y + v.z * v.z + v.w * v.w;
  }
#pragma unroll
  for (int off = 32; off; off >>= 1) { s += __shfl_down(s, off); ss += __shfl_down(ss, off); }
  __shared__ float as_[4], ass_[4];
  int w = threadIdx.x >> 6;
  if ((threadIdx.x & 63) == 0) { as_[w] = s; ass_[w] = ss; }
  __syncthreads();
  if (threadIdx.x == 0) {
    float S = as_[0] + as_[1] + as_[2] + as_[3];
    float SS = ass_[0] + ass_[1] + ass_[2] + ass_[3];
    float mu = S * (1.0f / N_);
    float var = (SS - (float)N_ * mu * mu) * (1.0f / (N_ - 1));
    stats[(size_t)(b * C_ + c) * 2 + 0] = mu;
    stats[(size_t)(b * C_ + c) * 2 + 1] = rsqrtf(var + 1e-5f);
  }
}

// ------- out[b][c][n] = sqrt(relu(sec-mean^2))*(x-mu)*rs + mean ; mean/sec f16 [n][c] -------
__global__ __launch_bounds__(256) void combine_kernel(const float* __restrict__ content,
                                                      const u16* __restrict__ meanb,
                                                      const u16* __restrict__ secb,
                                                      const float* __restrict__ stats,
                                                      float* __restrict__ outp) {
  __shared__ float ldM[64][65], ldS[64][65];
  const int b = blockIdx.z, n0 = blockIdx.x * 64, c0 = blockIdx.y * 64;
  const int t = threadIdx.x;
  {
    const int r = t >> 2, q4 = (t & 3) * 16;
    size_t ib = ((size_t)(b * N_ + n0 + r)) * C_ + c0 + q4;
#pragma unroll
    for (int j = 0; j < 2; ++j) {
      uint4 mv = *(const uint4*)(meanb + ib + j * 8);
      uint4 sv = *(const uint4*)(secb + ib + j * 8);
      const unsigned* mw = (const unsigned*)&mv;
      const unsigned* sw = (const unsigned*)&sv;
#pragma unroll
      for (int k = 0; k < 4; ++k) {
        ldM[r][q4 + j * 8 + k * 2 + 0] = h2f((u16)(mw[k] & 0xffff));
        ldM[r][q4 + j * 8 + k * 2 + 1] = h2f((u16)(mw[k] >> 16));
        ldS[r][q4 + j * 8 + k * 2 + 0] = h2f((u16)(sw[k] & 0xffff));
        ldS[r][q4 + j * 8 + k * 2 + 1] = h2f((u16)(sw[k] >> 16));
      }
    }
  }
  __syncthreads();
  const int n4 = (t & 15) * 4, cb = t >> 4;
#pragma unroll
  for (int cc = 0; cc < 4; ++cc) {
    int c_loc = cc * 16 + cb;
    int c = c0 + c_loc;
    float mu = stats[(size_t)(b * C_ + c) * 2 + 0];
    float rs = stats[(size_t)(b * C_ + c) * 2 + 1];
    size_t gb = ((size_t)(b * C_ + c)) * N_ + n0 + n4;
    float4 xv = *(const float4*)(content + gb);
    float4 ov;
    {
      float m0_ = ldM[n4 + 0][c_loc], s0_ = ldS[n4 + 0][c_loc];
      float m1_ = ldM[n4 + 1][c_loc], s1_ = ldS[n4 + 1][c_loc];
      float m2_ = ldM[n4 + 2][c_loc], s2_ = ldS[n4 + 2][c_loc];
      float m3_ = ldM[n4 + 3][c_loc], s3_ = ldS[n4 + 3][c_loc];
      ov.x = sqrtf(fmaxf(s0_ - m0_ * m0_, 0.f)) * ((xv.x - mu) * rs) + m0_;
      ov.y = sqrtf(fmaxf(s1_ - m1_ * m1_, 0.f)) * ((xv.y - mu) * rs) + m1_;
      ov.z = sqrtf(fmaxf(s2_ - m2_ * m2_, 0.f)) * ((xv.z - mu) * rs) + m2_;
      ov.w = sqrtf(fmaxf(s3_ - m3_ * m3_, 0.f)) * ((xv.w - mu) * rs) + m3_;
    }
    *(float4*)(outp + gb) = ov;
  }
}

extern "C" void kernel_launch(void* const* d_in, const int* in_sizes, int n_in,
                              void* d_out, int out_size, void* d_ws, size_t ws_size,
                              hipStream_t stream) {
  (void)in_sizes; (void)n_in; (void)out_size; (void)ws_size;
  const float* content = (const float*)d_in[0];
  const float* style   = (const float*)d_in[1];
  const float* ckey    = (const float*)d_in[2];
  const float* skey    = (const float*)d_in[3];
  const float* Wf = (const float*)d_in[4]; const float* bf_ = (const float*)d_in[5];
  const float* Wg = (const float*)d_in[6]; const float* bg_ = (const float*)d_in[7];
  const float* Wh = (const float*)d_in[8]; const float* bh_ = (const float*)d_in[9];
  float* outp = (float*)d_out;
  char* ws = (char*)d_ws;

  const size_t MB = 1u << 20;
  u16*   Ft    = (u16*)(ws + 0 * MB);    // [B][N][C] f16 (16MB)
  u16*   Gt    = (u16*)(ws + 16 * MB);   // [B][M][C] f16 (16MB)
  u16*   Hv    = (u16*)(ws + 32 * MB);   // [B][C][M] f16 (16MB, conv-H transposed)
  float* stats = (float*)(ws + 48 * MB); // [B][C][2] fp32
  u16*   meanb = (u16*)(ws + 64 * MB);   // [B][N][C] f16 (16MB)
  u16*   secb  = (u16*)(ws + 96 * MB);   // [B][N][C] f16 (16MB)
  u16*   Wb3   = (u16*)(ws + 80 * MB);   // weights f16 (1.5MB), dead before attn
  u16* Wbf = Wb3, *Wbg = Wb3 + 262144, *Wbh = Wb3 + 524288;

  const dim3 gT(64, 8, 4);
  const dim3 gC(64, B_);

  cast_w_kernel<<<256, 256, 0, stream>>>(Wf, Wbf, 262144);
  cast_w_kernel<<<256, 256, 0, stream>>>(Wg, Wbg, 262144);
  cast_w_kernel<<<256, 256, 0, stream>>>(Wh, Wbh, 262144);

  conv_fused_kernel<<<gC, 512, 0, stream>>>(ckey, Wbf, bf_, Ft, nullptr);
  conv_fused_kernel<<<gC, 512, 0, stream>>>(skey, Wbg, bg_, Gt, nullptr);
  conv_fused_kernel<<<gC, 512, 0, stream>>>(style, Wbh, bh_, nullptr, Hv);

  stats_kernel<<<dim3(C_, B_), 256, 0, stream>>>(content, stats);
  attn_dual_kernel<<<dim3(64, B_), 1024, 0, stream>>>(Ft, Gt, Hv, meanb, secb);
  combine_kernel<<<gT, 256, 0, stream>>>(content, meanb, secb, stats, outp);
}